// Round 6
// baseline (183.084 us; speedup 1.0000x reference)
//
#include <hip/hip_runtime.h>
#include <hip/hip_bf16.h>

#define E_ 8
#define D_ 1024
#define H_ 4096
#define T_ 512
#define A_ 1024  // total assignments = T_ * top_k
#define BM_ 192  // covers count<=192 in one pass
#define NBUF 4

typedef __attribute__((ext_vector_type(8))) short bf16x8;
typedef __attribute__((ext_vector_type(4))) float f32x4;

__device__ __forceinline__ unsigned short f2bf(float f) {
  __hip_bfloat16 h = __float2bfloat16(f);
  return *reinterpret_cast<unsigned short*>(&h);
}

__device__ __forceinline__ bf16x8 pk8(float4 a, float4 b) {
  bf16x8 r;
  r[0] = (short)f2bf(a.x); r[1] = (short)f2bf(a.y);
  r[2] = (short)f2bf(a.z); r[3] = (short)f2bf(a.w);
  r[4] = (short)f2bf(b.x); r[5] = (short)f2bf(b.y);
  r[6] = (short)f2bf(b.z); r[7] = (short)f2bf(b.w);
  return r;
}

// async global->LDS, 16B per lane; dest = wave-uniform base + lane*16
__device__ __forceinline__ void gl16(const void* g, void* l) {
  __builtin_amdgcn_global_load_lds(
      (const __attribute__((address_space(1))) unsigned int*)g,
      (__attribute__((address_space(3))) unsigned int*)l, 16, 0, 0);
}

#define WV3 asm volatile("s_waitcnt vmcnt(3)" ::: "memory")
#define WV4 asm volatile("s_waitcnt vmcnt(4)" ::: "memory")
#define WV5 asm volatile("s_waitcnt vmcnt(5)" ::: "memory")
#define WV0 asm volatile("s_waitcnt vmcnt(0)" ::: "memory")
#define BARX do { __builtin_amdgcn_s_barrier(); __builtin_amdgcn_sched_barrier(0); } while (0)

// ---------------- Router ----------------------------------------------------
__global__ void moe_router(const float* __restrict__ x,
                           const float* __restrict__ gw,
                           unsigned short* __restrict__ xb,
                           int* __restrict__ sel,
                           float* __restrict__ wtop) {
  const int t = blockIdx.x;
  const int lane = threadIdx.x;  // 64
  const float* xr = x + (size_t)t * D_;

  float4 xv[4];
#pragma unroll
  for (int i = 0; i < 4; ++i) xv[i] = *reinterpret_cast<const float4*>(xr + (i * 64 + lane) * 4);
#pragma unroll
  for (int i = 0; i < 4; ++i) {
    ushort4 u;
    u.x = f2bf(xv[i].x); u.y = f2bf(xv[i].y); u.z = f2bf(xv[i].z); u.w = f2bf(xv[i].w);
    *reinterpret_cast<ushort4*>(xb + (size_t)t * D_ + (i * 64 + lane) * 4) = u;
  }

  float lg[E_];
  for (int e = 0; e < E_; ++e) {
    const float* g = gw + (size_t)e * D_;
    float p = 0.f;
#pragma unroll
    for (int i = 0; i < 4; ++i) {
      float4 gv = *reinterpret_cast<const float4*>(g + (i * 64 + lane) * 4);
      p += xv[i].x * gv.x + xv[i].y * gv.y + xv[i].z * gv.z + xv[i].w * gv.w;
    }
#pragma unroll
    for (int off = 32; off; off >>= 1) p += __shfl_xor(p, off);
    lg[e] = p;
  }
  if (lane == 0) {
    float m = lg[0];
    for (int e = 1; e < E_; ++e) m = fmaxf(m, lg[e]);
    float pr[E_];
    float s = 0.f;
    for (int e = 0; e < E_; ++e) { pr[e] = __expf(lg[e] - m); s += pr[e]; }
    const float inv = 1.f / s;
    for (int e = 0; e < E_; ++e) pr[e] *= inv;
    float v0 = -1.f, v1 = -1.f; int i0 = 0, i1 = 0;
    for (int e = 0; e < E_; ++e) {
      float p = pr[e];
      if (p > v0)      { v1 = v0; i1 = i0; v0 = p; i0 = e; }
      else if (p > v1) { v1 = p; i1 = e; }
    }
    const float s2 = 1.f / (v0 + v1);
    sel[2 * t] = i0; sel[2 * t + 1] = i1;
    wtop[2 * t] = v0 * s2; wtop[2 * t + 1] = v1 * s2;
  }
}

// ---------------- Compaction: deterministic, order-preserving ---------------
__global__ void moe_compact(const int* __restrict__ sel,
                            const float* __restrict__ wtop,
                            int* __restrict__ counts,
                            int* __restrict__ offsets,
                            int* __restrict__ tok,
                            int* __restrict__ slotof,
                            float* __restrict__ coef) {
  const int tid = threadIdx.x;  // 512 = 8 waves; wave = expert
  const int e = tid >> 6;
  const int lane = tid & 63;
  __shared__ int cnt[E_], offs[E_];

  int base = 0;
  for (int c = 0; c < T_ / 64; ++c) {
    const int t = c * 64 + lane;
    const bool f = (sel[2 * t] == e) || (sel[2 * t + 1] == e);
    base += __popcll(__ballot(f));
  }
  if (lane == 0) cnt[e] = base;
  __syncthreads();
  if (tid == 0) {
    int o = 0;
    for (int i = 0; i < E_; ++i) { offs[i] = o; o += cnt[i]; }
  }
  __syncthreads();
  if (lane == 0) { counts[e] = cnt[e]; offsets[e] = offs[e]; }

  int pos = offs[e];
  for (int c = 0; c < T_ / 64; ++c) {
    const int t = c * 64 + lane;
    const int s0 = sel[2 * t], s1 = sel[2 * t + 1];
    const bool f = (s0 == e) || (s1 == e);
    unsigned long long b = __ballot(f);
    const int myp = pos + __popcll(b & ((1ull << lane) - 1ull));
    if (f) {
      const int k = (s0 == e) ? 0 : 1;
      tok[myp] = t;
      slotof[2 * t + k] = myp;
      coef[myp] = wtop[2 * t + k];
    }
    pos += __popcll(b);
  }
}

// ---------------- FFN1: BN=32, NBUF=4, counted-vmcnt, A in regs -------------
// Per wave per K-step: stage 2 gl16 (B1+B3 row-octet), 3 A dwordx4, 12 MFMA.
// Ledger (body tau>=1): younger-than-A(tau) = S(tau+2)[2] + A(tau+1)[3] = 5.
// Tail uniformity via dummy re-stage of last tile into the dead slot.

#define STAGE1(S, KT)                                                        \
  do {                                                                       \
    gl16(b1p + (KT) * 32, B1s + (S) * 1024 + wid * 256);                     \
    gl16(b3p + (KT) * 32, B3s + (S) * 1024 + wid * 256);                     \
  } while (0)

#define LOADA1(SET, KA)                                                      \
  do {                                                                       \
    _Pragma("unroll")                                                        \
    for (int mf = 0; mf < 3; ++mf)                                           \
      SET[mf] = *reinterpret_cast<const bf16x8*>(ap[mf] + (KA) * 32);        \
  } while (0)

#define MFMA1(RD, ASET)                                                      \
  do {                                                                       \
    const float* bb1 = B1s + (RD) * 1024;                                    \
    const float* bb3 = B3s + (RD) * 1024;                                    \
    _Pragma("unroll")                                                        \
    for (int nf = 0; nf < 2; ++nf) {                                         \
      const int rb = (nf * 16 + lr) * 32;                                    \
      bf16x8 b1f = pk8(*reinterpret_cast<const float4*>(bb1 + rb + q0),      \
                       *reinterpret_cast<const float4*>(bb1 + rb + q1));     \
      bf16x8 b3f = pk8(*reinterpret_cast<const float4*>(bb3 + rb + q0),      \
                       *reinterpret_cast<const float4*>(bb3 + rb + q1));     \
      _Pragma("unroll")                                                      \
      for (int mf = 0; mf < 3; ++mf)                                         \
        if (mf < mfn) {                                                      \
          acc1[mf][nf] = __builtin_amdgcn_mfma_f32_16x16x32_bf16(ASET[mf], b1f, acc1[mf][nf], 0, 0, 0); \
          acc3[mf][nf] = __builtin_amdgcn_mfma_f32_16x16x32_bf16(ASET[mf], b3f, acc3[mf][nf], 0, 0, 0); \
        }                                                                    \
    }                                                                        \
  } while (0)

__launch_bounds__(256, 4)
__global__ void moe_ffn1(const unsigned short* __restrict__ xb,
                         const float* __restrict__ w1,
                         const float* __restrict__ w3,
                         const int* __restrict__ counts,
                         const int* __restrict__ offsets,
                         const int* __restrict__ tok,
                         unsigned short* __restrict__ act) {
  const int bid = blockIdx.x;
  const int e = bid & 7;        // XCD-pinned: expert -> one XCD's L2
  const int hg = bid >> 3;      // 128 h-groups of 32 cols
  const int count = counts[e];
  const int off = offsets[e];
  const int hbase = hg * 32;

  __shared__ float B1s[NBUF * 1024];  // 16 KB
  __shared__ float B3s[NBUF * 1024];  // 16 KB

  const int tid = threadIdx.x;
  const int lane = tid & 63, wid = tid >> 6;
  const int lr = lane & 15, kg = lane >> 4;
  const int wm = wid * 48;

  // staging source: row = hbase + wid*8 + (lane>>3); col-quad pre-swizzled
  const int cB = (((lane & 7) ^ (lane >> 3)) << 2);
  const float* b1p = w1 + ((size_t)e * H_ + hbase + wid * 8 + (lane >> 3)) * D_ + cB;
  const float* b3p = w3 + ((size_t)e * H_ + hbase + wid * 8 + (lane >> 3)) * D_ + cB;
  // swizzled read offsets (float units)
  const int q0 = (((2 * kg) ^ (lr & 7)) << 2);
  const int q1 = (((2 * kg + 1) ^ (lr & 7)) << 2);

  for (int m0 = 0; m0 < count; m0 += BM_) {
    const unsigned short* ap[3];
#pragma unroll
    for (int mf = 0; mf < 3; ++mf) {
      const int row = m0 + wm + mf * 16 + lr;
      const int cr = (row < count) ? row : (count - 1);
      ap[mf] = xb + (size_t)tok[off + cr] * D_ + kg * 8;
    }
    const int qq = count - m0 - wm;
    const int mfn = (qq <= 0) ? 0 : ((qq + 15) >> 4 < 3 ? (qq + 15) >> 4 : 3);

    f32x4 acc1[3][2] = {};
    f32x4 acc3[3][2] = {};
    bf16x8 aE[3], aO[3];

    STAGE1(0, 0); STAGE1(1, 1); STAGE1(2, 2);
    LOADA1(aE, 0); LOADA1(aO, 1);

    int rd = 0;
    for (int t = 0; t < 32; t += 2) {
      // ---- body tau = t (even), uses aE = A(t)
      if (t == 0) { WV3; } else { WV5; }
      BARX;
      { int s = rd + 3; if (s >= NBUF) s -= NBUF;
        int kt = t + 3; if (kt > 31) kt = 31; STAGE1(s, kt); }
      __builtin_amdgcn_s_setprio(1);
      MFMA1(rd, aE);
      __builtin_amdgcn_s_setprio(0);
      { int ka = t + 2; if (ka > 31) ka = 31; LOADA1(aE, ka); }
      ++rd; if (rd == NBUF) rd = 0;

      // ---- body tau = t+1 (odd), uses aO = A(t+1)
      WV5;
      BARX;
      { int s = rd + 3; if (s >= NBUF) s -= NBUF;
        int kt = t + 4; if (kt > 31) kt = 31; STAGE1(s, kt); }
      __builtin_amdgcn_s_setprio(1);
      MFMA1(rd, aO);
      __builtin_amdgcn_s_setprio(0);
      { int ka = t + 3; if (ka > 31) ka = 31; LOADA1(aO, ka); }
      ++rd; if (rd == NBUF) rd = 0;
    }

    // Epilogue: silu(h1)*h3 -> bf16 act
#pragma unroll
    for (int mf = 0; mf < 3; ++mf) {
#pragma unroll
      for (int r = 0; r < 4; ++r) {
        const int mrow = m0 + wm + mf * 16 + kg * 4 + r;
        if (mrow < count) {
          const size_t rb = (size_t)(off + mrow) * H_;
#pragma unroll
          for (int nf = 0; nf < 2; ++nf) {
            const float h1 = acc1[mf][nf][r];
            const float h3 = acc3[mf][nf][r];
            const float a = h1 / (1.f + __expf(-h1)) * h3;
            act[rb + hbase + nf * 16 + lr] = f2bf(a);
          }
        }
      }
    }
    WV0;
    __syncthreads();  // rare multi-pass: drain dummies, protect LDS
  }
}

// ---------------- FFN2: same structure, one B matrix, split-K ---------------
#define STAGE2(S, KT) gl16(b2p + (KT) * 32, Bs + (S) * 1024 + wid * 256)

#define LOADA2(SET, KA)                                                      \
  do {                                                                       \
    _Pragma("unroll")                                                        \
    for (int mf = 0; mf < 3; ++mf)                                           \
      SET[mf] = *reinterpret_cast<const bf16x8*>(ap[mf] + (KA) * 32);        \
  } while (0)

#define MFMA2(RD, ASET)                                                      \
  do {                                                                       \
    const float* bb = Bs + (RD) * 1024;                                      \
    _Pragma("unroll")                                                        \
    for (int nf = 0; nf < 2; ++nf) {                                         \
      const int rb = (nf * 16 + lr) * 32;                                    \
      bf16x8 bf = pk8(*reinterpret_cast<const float4*>(bb + rb + q0),        \
                      *reinterpret_cast<const float4*>(bb + rb + q1));       \
      _Pragma("unroll")                                                      \
      for (int mf = 0; mf < 3; ++mf)                                         \
        if (mf < mfn)                                                        \
          acc[mf][nf] = __builtin_amdgcn_mfma_f32_16x16x32_bf16(ASET[mf], bf, acc[mf][nf], 0, 0, 0); \
    }                                                                        \
  } while (0)

__launch_bounds__(256, 4)
__global__ void moe_ffn2(const unsigned short* __restrict__ act,
                         const float* __restrict__ w2,
                         const int* __restrict__ counts,
                         const int* __restrict__ offsets,
                         const float* __restrict__ coef,
                         float* __restrict__ part,
                         int kschunk) {
  const int bid = blockIdx.x;
  const int e = bid & 7;        // XCD-pinned
  const int rest = bid >> 3;
  const int dg = rest & 31;     // 32 d-groups of 32 cols
  const int ks = rest >> 5;
  const int count = counts[e];
  const int off = offsets[e];
  const int dbase = dg * 32;
  const int kbase = ks * kschunk;
  const int nit = kschunk >> 5;   // 32/64/128 (even)

  __shared__ float Bs[NBUF * 1024];  // 16 KB

  const int tid = threadIdx.x;
  const int lane = tid & 63, wid = tid >> 6;
  const int lr = lane & 15, kg = lane >> 4;
  const int wm = wid * 48;

  const int cB = (((lane & 7) ^ (lane >> 3)) << 2);
  const float* b2p = w2 + ((size_t)e * D_ + dbase + wid * 8 + (lane >> 3)) * H_ + kbase + cB;
  const int q0 = (((2 * kg) ^ (lr & 7)) << 2);
  const int q1 = (((2 * kg + 1) ^ (lr & 7)) << 2);

  for (int m0 = 0; m0 < count; m0 += BM_) {
    const unsigned short* ap[3];
#pragma unroll
    for (int mf = 0; mf < 3; ++mf) {
      const int row = m0 + wm + mf * 16 + lr;
      const int cr = (row < count) ? row : (count - 1);
      ap[mf] = act + (size_t)(off + cr) * H_ + kbase + kg * 8;
    }
    const int qq = count - m0 - wm;
    const int mfn = (qq <= 0) ? 0 : ((qq + 15) >> 4 < 3 ? (qq + 15) >> 4 : 3);

    f32x4 acc[3][2] = {};
    bf16x8 aE[3], aO[3];

    STAGE2(0, 0); STAGE2(1, 1); STAGE2(2, 2);
    LOADA2(aE, 0); LOADA2(aO, 1);

    int rd = 0;
    const int last = nit - 1;
    for (int t = 0; t < nit; t += 2) {
      if (t == 0) { WV3; } else { WV4; }
      BARX;
      { int s = rd + 3; if (s >= NBUF) s -= NBUF;
        int kt = t + 3; if (kt > last) kt = last; STAGE2(s, kt); }
      __builtin_amdgcn_s_setprio(1);
      MFMA2(rd, aE);
      __builtin_amdgcn_s_setprio(0);
      { int ka = t + 2; if (ka > last) ka = last; LOADA2(aE, ka); }
      ++rd; if (rd == NBUF) rd = 0;

      WV4;
      BARX;
      { int s = rd + 3; if (s >= NBUF) s -= NBUF;
        int kt = t + 4; if (kt > last) kt = last; STAGE2(s, kt); }
      __builtin_amdgcn_s_setprio(1);
      MFMA2(rd, aO);
      __builtin_amdgcn_s_setprio(0);
      { int ka = t + 3; if (ka > last) ka = last; LOADA2(aO, ka); }
      ++rd; if (rd == NBUF) rd = 0;
    }

#pragma unroll
    for (int mf = 0; mf < 3; ++mf) {
#pragma unroll
      for (int r = 0; r < 4; ++r) {
        const int mrow = m0 + wm + mf * 16 + kg * 4 + r;
        if (mrow < count) {
          const float cf = coef[off + mrow];
          float* prow = part + ((size_t)ks * A_ + off + mrow) * D_;
#pragma unroll
          for (int nf = 0; nf < 2; ++nf)
            prow[dbase + nf * 16 + lr] = cf * acc[mf][nf][r];
        }
      }
    }
    WV0;
    __syncthreads();
  }
}

// out[t] = sum over (ksn x 2 slots) partials in fixed order -> deterministic
__global__ void moe_combine(const float* __restrict__ part,
                            const int* __restrict__ slotof,
                            float* __restrict__ out,
                            int ksn) {
  const int t = blockIdx.x;
  const int i = threadIdx.x;  // 256 threads, float4 each
  const int g0 = slotof[2 * t], g1 = slotof[2 * t + 1];
  float4 o = make_float4(0.f, 0.f, 0.f, 0.f);
  for (int ks = 0; ks < ksn; ++ks) {
    const float* p = part + (size_t)ks * A_ * D_;
    float4 a = reinterpret_cast<const float4*>(p + (size_t)g0 * D_)[i];
    float4 b = reinterpret_cast<const float4*>(p + (size_t)g1 * D_)[i];
    o.x += a.x + b.x; o.y += a.y + b.y; o.z += a.z + b.z; o.w += a.w + b.w;
  }
  reinterpret_cast<float4*>(out + (size_t)t * D_)[i] = o;
}

extern "C" void kernel_launch(void* const* d_in, const int* in_sizes, int n_in,
                              void* d_out, int out_size, void* d_ws, size_t ws_size,
                              hipStream_t stream) {
  const float* x  = (const float*)d_in[0];
  const float* gw = (const float*)d_in[1];
  const float* w1 = (const float*)d_in[2];
  const float* w3 = (const float*)d_in[3];
  const float* w2 = (const float*)d_in[4];
  float* out = (float*)d_out;

  char* ws = (char*)d_ws;
  const size_t SM   = 32768;
  const size_t ACT  = (size_t)A_ * H_ * 2;   // 8 MB bf16
  const size_t XB   = (size_t)T_ * D_ * 2;   // 1 MB bf16
  const size_t P1   = (size_t)A_ * D_ * 4;   // 4 MB fp32 per K-split

  char* sm = ws;
  unsigned short* act = (unsigned short*)(ws + SM);
  unsigned short* xb  = (unsigned short*)(ws + SM + ACT);
  float* part         = (float*)(ws + SM + ACT + XB);
  const size_t base = SM + ACT + XB;
  const int ksn = (ws_size >= base + 8 * P1) ? 8 :
                  (ws_size >= base + 4 * P1) ? 4 :
                  (ws_size >= base + 2 * P1) ? 2 : 1;

  int*   sel     = (int*)  (sm);
  float* wtop    = (float*)(sm + 4096);
  int*   counts  = (int*)  (sm + 8192);
  int*   offsets = (int*)  (sm + 8192 + 64);
  int*   tokl    = (int*)  (sm + 12288);
  int*   slotof  = (int*)  (sm + 16384);
  float* coef    = (float*)(sm + 20480);

  moe_router <<<T_, 64, 0, stream>>>(x, gw, xb, sel, wtop);
  moe_compact<<<1, 512, 0, stream>>>(sel, wtop, counts, offsets, tokl, slotof, coef);
  moe_ffn1   <<<E_ * 128, 256, 0, stream>>>(xb, w1, w3, counts, offsets, tokl, act);
  moe_ffn2   <<<E_ * 32 * ksn, 256, 0, stream>>>(act, w2, counts, offsets, coef, part, H_ / ksn);
  moe_combine<<<T_, 256, 0, stream>>>(part, slotof, out, ksn);
}